// Round 17
// baseline (187.184 us; speedup 1.0000x reference)
//
#include <hip/hip_runtime.h>
#include <hip/hip_bf16.h>

typedef __bf16 bf16_t;
typedef bf16_t bf16x8 __attribute__((ext_vector_type(8)));
typedef bf16_t bf16x4 __attribute__((ext_vector_type(4)));
typedef float  f32x4  __attribute__((ext_vector_type(4)));
typedef float  f32x8  __attribute__((ext_vector_type(8)));
typedef float  f32x16 __attribute__((ext_vector_type(16)));

#define B_  4
#define S_  2048
#define D_  1024
#define H_  16
#define HD  64

// 0.125 (d^-0.5) * log2(e): folded into q so QK^T score is the exp2 argument directly
#define QSCALE 0.1803368801111204f

// kv_frag geometry: [bh][tile(64)][chunk(8)][512 bf16]; chunks 0-3 = K frags, 4-7 = V frags
#define KV_TILE_ELEMS 4096
#define KV_BH_ELEMS   262144

__device__ __forceinline__ float fast_exp2(float x) {
    float r;
    asm("v_exp_f32 %0, %1" : "=v"(r) : "v"(x));
    return r;
}

// ---------------- fp32 (R x 1024) -> FRAGMENT-NATIVE bf16 ----------------
// frag[mt][ks][l*8+j] = M[mt*16 + (l&15)][ks*32 + (l>>4)*8 + j]  (mt = row/16, ks = col/32)
// This is exactly the per-lane A/B fragment of mfma_f32_16x16x32_bf16: all GEMM loads become
// base + (mt*32+ks)*1KB + lane*16B -> fully coalesced (the round-9 attn unlock, applied to GEMM).
__global__ __launch_bounds__(256) void cvt_frag_kernel(const float* __restrict__ src,
                                                       bf16_t* __restrict__ dst) {
    __shared__ __align__(16) bf16_t T[16][1032];
    const int mt = blockIdx.x;
    const int t  = threadIdx.x;
    {
        const int r  = t >> 4;
        const int c0 = (t & 15) * 64;
        const float* s = src + ((size_t)mt * 16 + r) * 1024 + c0;
        #pragma unroll
        for (int i = 0; i < 16; ++i) {
            float4 f = ((const float4*)s)[i];
            bf16x4 o = { (bf16_t)f.x, (bf16_t)f.y, (bf16_t)f.z, (bf16_t)f.w };
            *(bf16x4*)&T[r][c0 + i * 4] = o;
        }
    }
    __syncthreads();
    {
        bf16_t* base = dst + (size_t)mt * 32 * 512;
        #pragma unroll
        for (int i = 0; i < 8; ++i) {
            const int idx = i * 256 + t;
            const int ks = idx >> 6, l = idx & 63;
            bf16x8 o = *(const bf16x8*)&T[l & 15][ks * 32 + ((l >> 4) & 3) * 8];
            *(bf16x8*)(base + (size_t)ks * 512 + l * 8) = o;
        }
    }
}

// ---------------- fragment-streaming GEMM core: no LDS, no barriers (attn-calibrated) ----------
// Per wave: 4 m-tiles x 4 n-tiles (64x64 output). Per K-step: 8 coalesced 16B loads + 16 MFMA.
__device__ __forceinline__ void frag_gemm_core(const bf16_t* __restrict__ afrag,
                                               const bf16_t* __restrict__ bfrag,
                                               int mtBase, int ntBase, int lane,
                                               f32x4 acc[4][4]) {
    const bf16_t* ap = afrag + (size_t)mtBase * 32 * 512 + lane * 8;
    const bf16_t* bp = bfrag + (size_t)ntBase * 32 * 512 + lane * 8;
    #pragma unroll 1
    for (int ks = 0; ks < 32; ++ks) {
        bf16x8 aF[4], bF[4];
        #pragma unroll
        for (int i = 0; i < 4; ++i) aF[i] = *(const bf16x8*)(ap + (size_t)(i * 32 + ks) * 512);
        #pragma unroll
        for (int i = 0; i < 4; ++i) bF[i] = *(const bf16x8*)(bp + (size_t)(i * 32 + ks) * 512);
        #pragma unroll
        for (int m = 0; m < 4; ++m)
            #pragma unroll
            for (int n = 0; n < 4; ++n)
                acc[m][n] = __builtin_amdgcn_mfma_f32_16x16x32_bf16(aF[m], bF[n], acc[m][n], 0, 0, 0);
    }
}

// ---------------- GEMM 1: qkv = x @ w_qkv^T (fragment streaming, 128x128 block) ----------------
// XCD m-striping: xcd = bid&7 owns an m-stripe -> its 2 MB A-panel stays L2-resident;
// B (6.3 MB) streams via L3. Epilogue identical to the round-11-verified 128^2 scatter.
__global__ __launch_bounds__(256) void gemm_qkv_kernel(const bf16_t* __restrict__ afrag,
                                                       const bf16_t* __restrict__ wfrag,
                                                       float* __restrict__ out,
                                                       bf16_t* __restrict__ q_ws,
                                                       bf16_t* __restrict__ kv_frag) {
    const int bid = blockIdx.x;                 // 0..1535
    const int xcd = bid & 7, idx = bid >> 3;    // idx 0..191
    const int m_blk = xcd * 8 + (idx & 7);      // 0..63
    const int n_blk = idx >> 3;                 // 0..23
    const int lane = threadIdx.x & 63, wv = threadIdx.x >> 6;
    const int wm = wv >> 1, wn = wv & 1;

    f32x4 acc[4][4];
    #pragma unroll
    for (int m = 0; m < 4; ++m)
        #pragma unroll
        for (int n = 0; n < 4; ++n) acc[m][n] = f32x4{0.f, 0.f, 0.f, 0.f};

    frag_gemm_core(afrag, wfrag, m_blk * 8 + wm * 4, n_blk * 8 + wn * 4, lane, acc);

    const int m0 = m_blk * 128, n0 = n_blk * 128;
    const int lo = lane & 15, hi = lane >> 4;
    #pragma unroll
    for (int m = 0; m < 4; ++m) {
        #pragma unroll
        for (int n = 0; n < 4; ++n) {
            const int gcol = n0 + wn * 64 + n * 16 + lo;     // 0..3071
            const int sec  = gcol >> 10;                     // 0=q 1=k 2=v
            const int e    = gcol & 1023;
            const int h    = e >> 6, dv = e & 63;
            #pragma unroll
            for (int j4 = 0; j4 < 4; ++j4) {
                const int grow = m0 + wm * 64 + m * 16 + hi * 4 + j4;  // b*S+s
                const float v  = acc[m][n][j4];
                const int b = grow >> 11, s = grow & 2047;
                const size_t idx2 = ((((size_t)b * H_ + h) * S_ + s) << 6) + dv;
                if (sec == 0) {
                    q_ws[idx2] = (bf16_t)(v * QSCALE);  // scale folded into q
                } else if (sec == 1) {
                    out[8388608u + idx2] = v;      // k fp32 output
                    // fragment-native K store: chunk = dv>>4, lane-slot = hb*32 + ql
                    const int bh   = b * H_ + h;
                    const int tile = s >> 5, ql = s & 31;
                    const int c    = dv >> 4, hb = (dv >> 3) & 1, jj = dv & 7;
                    kv_frag[(((size_t)bh * 64 + tile) * 8 + c) * 512 + hb * 256 + ql * 8 + jj] = (bf16_t)v;
                } else {
                    out[16777216u + idx2] = v;     // v fp32 output
                }
            }
        }
    }
}

// ---------------- build V fragments: fp32 (B,H,S,64) -> kv_frag chunks 4..7 ----------------
__global__ __launch_bounds__(256) void build_vfrag_kernel(const float* __restrict__ v_f32,
                                                          bf16_t* __restrict__ kv_frag) {
    __shared__ __align__(16) bf16_t T[64][72];   // T[d][s_local]
    const int bh = blockIdx.x;
    const int s0 = blockIdx.y * 64;
    const int t  = threadIdx.x;
    {
        const int sl  = t >> 2;
        const int dv0 = (t & 3) * 16;
        const float* src = v_f32 + ((size_t)bh * S_ + s0 + sl) * HD + dv0;
        float tmp[16];
        #pragma unroll
        for (int i = 0; i < 4; ++i) *(float4*)(tmp + i * 4) = ((const float4*)src)[i];
        #pragma unroll
        for (int i = 0; i < 16; ++i) T[dv0 + i][sl] = (bf16_t)tmp[i];
    }
    __syncthreads();
    {
        const int st = t >> 7;
        const int r  = t & 127;
        const int cc = r >> 5;
        const int l  = r & 31;
        const int khi = cc >> 1, hd = cc & 1;
        const int d   = hd * 32 + l;
        const int tile = (s0 >> 5) + st;
        bf16_t* dst = kv_frag + (((size_t)bh * 64 + tile) * 8 + 4 + cc) * 512 + l * 8;
        const int slb = st * 32 + khi * 16;
        *(bf16x8*)(dst)       = *(const bf16x8*)&T[d][slb];       // hb = 0
        *(bf16x8*)(dst + 256) = *(const bf16x8*)&T[d][slb + 8];   // hb = 1
    }
}

// ---------------- flash attention (causal), wave-independent, 32x32 MFMA ----------------
// Fragment-native K/V loads; epilogue now writes OUTPUT IN FRAGMENT FORM (ofrag) so gemm_out
// can stream it without LDS.
__global__ __launch_bounds__(256) void attn_kernel(const bf16_t* __restrict__ q_ws,
                                                   const bf16_t* __restrict__ kv_frag,
                                                   bf16_t* __restrict__ ofrag) {
    __shared__ __align__(16) float MRG[2][2][64][20];
    __shared__ float LSUM[2][64];
    __shared__ __align__(16) bf16_t T[2][32][72];
    const int lane = threadIdx.x & 63;
    const int wv   = threadIdx.x >> 6;
    const int blk   = blockIdx.x;
    const int x     = blk & 7;
    const int r     = blk >> 3;
    const int bh    = x + 8 * (r & 7);
    const int pr    = wv >> 1;
    const int khalf = wv & 1;
    const int p     = (r >> 3) * 2 + pr;

    const int ql = lane & 31;
    const int hb = lane >> 5;
    const size_t kv_base = (size_t)bh * (S_ * HD);
    const int b = bh >> 4, h = bh & 15;

    const bf16_t* kvb = kv_frag + (size_t)bh * KV_BH_ELEMS + (size_t)lane * 8;

    auto load_k = [&](int tile, bf16x8 kf[4]) {
        const bf16_t* tp = kvb + (size_t)tile * KV_TILE_ELEMS;
        #pragma unroll
        for (int c = 0; c < 4; ++c) kf[c] = *(const bf16x8*)(tp + c * 512);
    };
    auto load_v = [&](int tile, bf16x8 vf[4]) {
        const bf16_t* tp = kvb + (size_t)tile * KV_TILE_ELEMS + 2048;
        #pragma unroll
        for (int i = 0; i < 4; ++i) vf[i] = *(const bf16x8*)(tp + i * 512);
    };

    #pragma unroll 1
    for (int pass = 0; pass < 2; ++pass) {
        const int qblock = pass ? (63 - p) : p;
        const int q0 = qblock * 32;
        const int nt  = qblock + 1;
        const int mid = nt >> 1;
        const int tstart = khalf ? mid : 0;
        const int tend   = khalf ? nt  : mid;

        bf16x8 qF[4];
        const bf16_t* qrow = q_ws + kv_base + (size_t)(q0 + ql) * HD + hb * 8;
        #pragma unroll
        for (int c = 0; c < 4; ++c) qF[c] = *(const bf16x8*)(qrow + 16 * c);

        f32x16 accT0 = {}, accT1 = {};
        float lsum = 0.f;

        auto compute_tile = [&](const bf16x8 kf[4], const bf16x8 vf[4], bool diag) {
            f32x16 s = {};
            #pragma unroll
            for (int c = 0; c < 4; ++c)
                s = __builtin_amdgcn_mfma_f32_32x32x16_bf16(kf[c], qF[c], s, 0, 0, 0);
            if (diag) {
                #pragma unroll
                for (int rr = 0; rr < 16; ++rr) {
                    const int kloc = (rr & 3) + 8 * (rr >> 2) + 4 * hb;
                    if (kloc > ql) s[rr] = -1e30f;
                }
            }
            #pragma unroll
            for (int rr = 0; rr < 16; ++rr) s[rr] = fast_exp2(s[rr]);
            f32x8 t8 = __builtin_shufflevector(s, s, 0, 1, 2, 3, 4, 5, 6, 7) +
                       __builtin_shufflevector(s, s, 8, 9, 10, 11, 12, 13, 14, 15);
            f32x4 t4 = __builtin_shufflevector(t8, t8, 0, 1, 2, 3) +
                       __builtin_shufflevector(t8, t8, 4, 5, 6, 7);
            lsum += (t4[0] + t4[1]) + (t4[2] + t4[3]);

            unsigned w[8];
            #pragma unroll
            for (int i = 0; i < 8; ++i) {
                unsigned d;
                asm("v_cvt_pk_bf16_f32 %0, %1, %2" : "=v"(d) : "v"(s[2 * i]), "v"(s[2 * i + 1]));
                w[i] = d;
            }
            union { unsigned u[4]; bf16x8 v; } pf0, pf1;
            {
                auto r0 = __builtin_amdgcn_permlane32_swap(w[0], w[2], false, false);
                auto r1 = __builtin_amdgcn_permlane32_swap(w[1], w[3], false, false);
                pf0.u[0] = r0[0]; pf0.u[1] = r1[0]; pf0.u[2] = r0[1]; pf0.u[3] = r1[1];
            }
            {
                auto r0 = __builtin_amdgcn_permlane32_swap(w[4], w[6], false, false);
                auto r1 = __builtin_amdgcn_permlane32_swap(w[5], w[7], false, false);
                pf1.u[0] = r0[0]; pf1.u[1] = r1[0]; pf1.u[2] = r0[1]; pf1.u[3] = r1[1];
            }

            accT0 = __builtin_amdgcn_mfma_f32_32x32x16_bf16(vf[0], pf0.v, accT0, 0, 0, 0);
            accT1 = __builtin_amdgcn_mfma_f32_32x32x16_bf16(vf[1], pf0.v, accT1, 0, 0, 0);
            accT0 = __builtin_amdgcn_mfma_f32_32x32x16_bf16(vf[2], pf1.v, accT0, 0, 0, 0);
            accT1 = __builtin_amdgcn_mfma_f32_32x32x16_bf16(vf[3], pf1.v, accT1, 0, 0, 0);
        };

        int t = tstart;
        for (; t + 1 < tend; t += 2) {
            bf16x8 kA[4], vA[4], kB[4], vB[4];
            load_k(t, kA);
            load_v(t, vA);
            load_k(t + 1, kB);
            load_v(t + 1, vB);
            compute_tile(kA, vA, t == qblock);
            compute_tile(kB, vB, (t + 1) == qblock);
        }
        if (t < tend) {
            bf16x8 kA[4], vA[4];
            load_k(t, kA);
            load_v(t, vA);
            compute_tile(kA, vA, t == qblock);
        }

        if (khalf) {
            *(f32x16*)&MRG[pr][0][lane][0] = accT0;
            *(f32x16*)&MRG[pr][1][lane][0] = accT1;
            LSUM[pr][lane] = lsum;
        }
        __syncthreads();
        if (!khalf) {
            accT0 += *(const f32x16*)&MRG[pr][0][lane][0];
            accT1 += *(const f32x16*)&MRG[pr][1][lane][0];
            lsum  += LSUM[pr][lane];
            const float ltot = lsum + __shfl_xor(lsum, 32, 64);
            const float inv  = 1.0f / ltot;
            #pragma unroll
            for (int rr = 0; rr < 16; ++rr) {
                const int dl = (rr & 3) + 8 * (rr >> 2) + 4 * hb;
                T[pr][ql][dl]      = (bf16_t)(accT0[rr] * inv);
                T[pr][ql][32 + dl] = (bf16_t)(accT1[rr] * inv);
            }
            asm volatile("s_waitcnt lgkmcnt(0)" ::: "memory");
            // fragment-native output: ofrag[mt][ks][l*8+j] = Out[mt*16+(l&15)][ks*32+(l>>4)*8+j]
            const int mtb = (b * S_ + q0) >> 4;
            #pragma unroll
            for (int c = 0; c < 4; ++c) {
                const int mt_l = c >> 1, ks_l = c & 1;
                bf16x8 o = *(const bf16x8*)&T[pr][mt_l * 16 + (lane & 15)]
                                             [ks_l * 32 + ((lane >> 4) & 3) * 8];
                *(bf16x8*)(ofrag + ((size_t)(mtb + mt_l) * 32 + h * 2 + ks_l) * 512 + lane * 8) = o;
            }
        }
        __syncthreads();
    }
}

// ---------------- GEMM 2: out = attn @ w_out^T (fragment streaming, fp32 store) ----------------
__global__ __launch_bounds__(256) void gemm_out_kernel(const bf16_t* __restrict__ ofrag,
                                                       const bf16_t* __restrict__ wofrag,
                                                       float* __restrict__ out) {
    const int bid = blockIdx.x;                 // 0..511
    const int xcd = bid & 7, idx = bid >> 3;    // idx 0..63
    const int m_blk = xcd * 8 + (idx & 7);      // 0..63
    const int n_blk = idx >> 3;                 // 0..7
    const int lane = threadIdx.x & 63, wv = threadIdx.x >> 6;
    const int wm = wv >> 1, wn = wv & 1;

    f32x4 acc[4][4];
    #pragma unroll
    for (int m = 0; m < 4; ++m)
        #pragma unroll
        for (int n = 0; n < 4; ++n) acc[m][n] = f32x4{0.f, 0.f, 0.f, 0.f};

    frag_gemm_core(ofrag, wofrag, m_blk * 8 + wm * 4, n_blk * 8 + wn * 4, lane, acc);

    const int m0 = m_blk * 128, n0 = n_blk * 128;
    const int lo = lane & 15, hi = lane >> 4;
    #pragma unroll
    for (int m = 0; m < 4; ++m) {
        #pragma unroll
        for (int n = 0; n < 4; ++n) {
            const int gcol = n0 + wn * 64 + n * 16 + lo;
            #pragma unroll
            for (int j = 0; j < 4; ++j) {
                const int grow = m0 + wm * 64 + m * 16 + hi * 4 + j;
                out[(size_t)grow * D_ + gcol] = acc[m][n][j];
            }
        }
    }
}

extern "C" void kernel_launch(void* const* d_in, const int* in_sizes, int n_in,
                              void* d_out, int out_size, void* d_ws, size_t ws_size,
                              hipStream_t stream) {
    (void)in_sizes; (void)n_in; (void)out_size; (void)ws_size;
    const float* x     = (const float*)d_in[0];
    // d_in[1] = mask (known causal, unused)
    const float* w_qkv = (const float*)d_in[2];
    const float* w_out = (const float*)d_in[3];
    float* out = (float*)d_out;
    char* ws = (char*)d_ws;

    bf16_t* afrag   = (bf16_t*)(ws);                 // 16,777,216 B (x fragment-native)
    bf16_t* wfrag   = (bf16_t*)(ws + 16777216);      //  6,291,456 B (w_qkv fragment-native)
    bf16_t* wofrag  = (bf16_t*)(ws + 23068672);      //  2,097,152 B (w_out fragment-native)
    bf16_t* q_ws    = (bf16_t*)(ws + 25165824);      // 16,777,216 B
    bf16_t* kv_frag = (bf16_t*)(ws + 41943040);      // 33,554,432 B (K+V fragment-native)
    bf16_t* ofrag   = (bf16_t*)(ws + 75497472);      // 16,777,216 B (attn out fragment-native)

    cvt_frag_kernel<<<512, 256, 0, stream>>>(x, afrag);
    cvt_frag_kernel<<<192, 256, 0, stream>>>(w_qkv, wfrag);
    cvt_frag_kernel<<<64, 256, 0, stream>>>(w_out, wofrag);

    gemm_qkv_kernel<<<1536, 256, 0, stream>>>(afrag, wfrag, out, q_ws, kv_frag);
    build_vfrag_kernel<<<dim3(64, 32), 256, 0, stream>>>(out + 16777216, kv_frag);
    attn_kernel<<<1024, 256, 0, stream>>>(q_ws, kv_frag, ofrag);
    gemm_out_kernel<<<512, 256, 0, stream>>>(ofrag, wofrag, out);
}

// Round 18
// 185.805 us; speedup vs baseline: 1.0074x; 1.0074x over previous
//
#include <hip/hip_runtime.h>
#include <hip/hip_bf16.h>

typedef __bf16 bf16_t;
typedef bf16_t bf16x8 __attribute__((ext_vector_type(8)));
typedef bf16_t bf16x4 __attribute__((ext_vector_type(4)));
typedef float  f32x4  __attribute__((ext_vector_type(4)));
typedef float  f32x8  __attribute__((ext_vector_type(8)));
typedef float  f32x16 __attribute__((ext_vector_type(16)));

#define B_  4
#define S_  2048
#define D_  1024
#define H_  16
#define HD  64

// 0.125 (d^-0.5) * log2(e): folded into q so QK^T score is the exp2 argument directly
#define QSCALE 0.1803368801111204f

// kv_frag geometry: [bh][tile(64)][chunk(8)][512 bf16]; chunks 0-3 = K frags, 4-7 = V frags
#define KV_TILE_ELEMS 4096
#define KV_BH_ELEMS   262144

__device__ __forceinline__ float fast_exp2(float x) {
    float r;
    asm("v_exp_f32 %0, %1" : "=v"(r) : "v"(x));
    return r;
}

// ---------------- fp32 (R x 1024) -> GROUPED FRAGMENT-NATIVE bf16 ----------------
// Grouped layout: dst[(((mt>>2)*32 + ks)*4 + (mt&3))*512 + l*8 + j]
//               = M[mt*16 + (l&15)][ks*32 + ((l>>4)&3)*8 + j]
// A wave's 4 consecutive m-subtiles for one K-step are CONTIGUOUS within 4KB -> the GEMM
// inner loop needs only ONE pointer bump (+4096B) per operand per K-step, loads use imm
// offsets sub*1024 (fits the 13-bit signed global imm). Kills the 16-VALU/step addressing.
__global__ __launch_bounds__(256) void cvt_frag_kernel(const float* __restrict__ src,
                                                       bf16_t* __restrict__ dst) {
    __shared__ __align__(16) bf16_t T[16][1032];
    const int mt = blockIdx.x;
    const int t  = threadIdx.x;
    {
        // r = t&15: 16 lanes of a quarter-wave span 16 DIFFERENT rows (bank stride 4, ~2-way)
        const int r  = t & 15;
        const int c0 = (t >> 4) * 64;
        const float* s = src + ((size_t)mt * 16 + r) * 1024 + c0;
        #pragma unroll
        for (int i = 0; i < 16; ++i) {
            float4 f = ((const float4*)s)[i];
            bf16x4 o = { (bf16_t)f.x, (bf16_t)f.y, (bf16_t)f.z, (bf16_t)f.w };
            *(bf16x4*)&T[r][c0 + i * 4] = o;
        }
    }
    __syncthreads();
    {
        const int mtg = mt >> 2, sub = mt & 3;
        bf16_t* base = dst + (((size_t)mtg * 32) * 4 + sub) * 512;
        #pragma unroll
        for (int i = 0; i < 8; ++i) {
            const int idx = i * 256 + t;
            const int ks = idx >> 6, l = idx & 63;
            bf16x8 o = *(const bf16x8*)&T[l & 15][ks * 32 + ((l >> 4) & 3) * 8];
            *(bf16x8*)(base + (size_t)ks * 2048 + l * 8) = o;
        }
    }
}

// ---------------- fragment-streaming GEMM core (grouped layout, 2 ptr-bumps/K-step) ------------
// Per wave: 64x64 output (acc 4x4). Per K-step: 8 coalesced 16B loads (imm offsets 0..3072) +
// 16 MFMA. mtBase/ntBase must be multiples of 4.
__device__ __forceinline__ void frag_gemm_core(const bf16_t* __restrict__ afrag,
                                               const bf16_t* __restrict__ bfrag,
                                               int mtBase, int ntBase, int lane,
                                               f32x4 acc[4][4]) {
    const bf16_t* a = afrag + (((size_t)(mtBase >> 2) * 32) * 4) * 512 + lane * 8;
    const bf16_t* b = bfrag + (((size_t)(ntBase >> 2) * 32) * 4) * 512 + lane * 8;
    #pragma unroll 1
    for (int ks = 0; ks < 32; ++ks) {
        bf16x8 aF[4], bF[4];
        #pragma unroll
        for (int i = 0; i < 4; ++i) aF[i] = *(const bf16x8*)(a + i * 512);
        #pragma unroll
        for (int i = 0; i < 4; ++i) bF[i] = *(const bf16x8*)(b + i * 512);
        #pragma unroll
        for (int m = 0; m < 4; ++m)
            #pragma unroll
            for (int n = 0; n < 4; ++n)
                acc[m][n] = __builtin_amdgcn_mfma_f32_16x16x32_bf16(aF[m], bF[n], acc[m][n], 0, 0, 0);
        a += 2048;
        b += 2048;
    }
}

// ---------------- GEMM 1: qkv = x @ w_qkv^T (fragment streaming, 128x128 block) ----------------
__global__ __launch_bounds__(256) void gemm_qkv_kernel(const bf16_t* __restrict__ afrag,
                                                       const bf16_t* __restrict__ wfrag,
                                                       float* __restrict__ out,
                                                       bf16_t* __restrict__ q_ws,
                                                       bf16_t* __restrict__ kv_frag) {
    const int bid = blockIdx.x;                 // 0..1535
    const int xcd = bid & 7, idx = bid >> 3;    // idx 0..191
    const int m_blk = xcd * 8 + (idx & 7);      // 0..63
    const int n_blk = idx >> 3;                 // 0..23
    const int lane = threadIdx.x & 63, wv = threadIdx.x >> 6;
    const int wm = wv >> 1, wn = wv & 1;

    f32x4 acc[4][4];
    #pragma unroll
    for (int m = 0; m < 4; ++m)
        #pragma unroll
        for (int n = 0; n < 4; ++n) acc[m][n] = f32x4{0.f, 0.f, 0.f, 0.f};

    frag_gemm_core(afrag, wfrag, m_blk * 8 + wm * 4, n_blk * 8 + wn * 4, lane, acc);

    const int m0 = m_blk * 128, n0 = n_blk * 128;
    const int lo = lane & 15, hi = lane >> 4;
    #pragma unroll
    for (int m = 0; m < 4; ++m) {
        #pragma unroll
        for (int n = 0; n < 4; ++n) {
            const int gcol = n0 + wn * 64 + n * 16 + lo;     // 0..3071
            const int sec  = gcol >> 10;                     // 0=q 1=k 2=v
            const int e    = gcol & 1023;
            const int h    = e >> 6, dv = e & 63;
            #pragma unroll
            for (int j4 = 0; j4 < 4; ++j4) {
                const int grow = m0 + wm * 64 + m * 16 + hi * 4 + j4;  // b*S+s
                const float v  = acc[m][n][j4];
                const int b = grow >> 11, s = grow & 2047;
                const size_t idx2 = ((((size_t)b * H_ + h) * S_ + s) << 6) + dv;
                if (sec == 0) {
                    q_ws[idx2] = (bf16_t)(v * QSCALE);  // scale folded into q
                } else if (sec == 1) {
                    out[8388608u + idx2] = v;      // k fp32 output
                    // fragment-native K store: chunk = dv>>4, lane-slot = hb*32 + ql
                    const int bh   = b * H_ + h;
                    const int tile = s >> 5, ql = s & 31;
                    const int c    = dv >> 4, hb = (dv >> 3) & 1, jj = dv & 7;
                    kv_frag[(((size_t)bh * 64 + tile) * 8 + c) * 512 + hb * 256 + ql * 8 + jj] = (bf16_t)v;
                } else {
                    out[16777216u + idx2] = v;     // v fp32 output
                }
            }
        }
    }
}

// ---------------- build V fragments: fp32 (B,H,S,64) -> kv_frag chunks 4..7 ----------------
__global__ __launch_bounds__(256) void build_vfrag_kernel(const float* __restrict__ v_f32,
                                                          bf16_t* __restrict__ kv_frag) {
    __shared__ __align__(16) bf16_t T[64][72];   // T[d][s_local]
    const int bh = blockIdx.x;
    const int s0 = blockIdx.y * 64;
    const int t  = threadIdx.x;
    {
        const int sl  = t >> 2;
        const int dv0 = (t & 3) * 16;
        const float* src = v_f32 + ((size_t)bh * S_ + s0 + sl) * HD + dv0;
        float tmp[16];
        #pragma unroll
        for (int i = 0; i < 4; ++i) *(float4*)(tmp + i * 4) = ((const float4*)src)[i];
        #pragma unroll
        for (int i = 0; i < 16; ++i) T[dv0 + i][sl] = (bf16_t)tmp[i];
    }
    __syncthreads();
    {
        const int st = t >> 7;
        const int r  = t & 127;
        const int cc = r >> 5;
        const int l  = r & 31;
        const int khi = cc >> 1, hd = cc & 1;
        const int d   = hd * 32 + l;
        const int tile = (s0 >> 5) + st;
        bf16_t* dst = kv_frag + (((size_t)bh * 64 + tile) * 8 + 4 + cc) * 512 + l * 8;
        const int slb = st * 32 + khi * 16;
        *(bf16x8*)(dst)       = *(const bf16x8*)&T[d][slb];       // hb = 0
        *(bf16x8*)(dst + 256) = *(const bf16x8*)&T[d][slb + 8];   // hb = 1
    }
}

// ---------------- flash attention (causal), wave-independent, 32x32 MFMA ----------------
// Fragment-native K/V loads; epilogue writes output in GROUPED fragment form for gemm_out.
__global__ __launch_bounds__(256) void attn_kernel(const bf16_t* __restrict__ q_ws,
                                                   const bf16_t* __restrict__ kv_frag,
                                                   bf16_t* __restrict__ ofrag) {
    __shared__ __align__(16) float MRG[2][2][64][20];
    __shared__ float LSUM[2][64];
    __shared__ __align__(16) bf16_t T[2][32][72];
    const int lane = threadIdx.x & 63;
    const int wv   = threadIdx.x >> 6;
    const int blk   = blockIdx.x;
    const int x     = blk & 7;
    const int r     = blk >> 3;
    const int bh    = x + 8 * (r & 7);
    const int pr    = wv >> 1;
    const int khalf = wv & 1;
    const int p     = (r >> 3) * 2 + pr;

    const int ql = lane & 31;
    const int hb = lane >> 5;
    const size_t kv_base = (size_t)bh * (S_ * HD);
    const int b = bh >> 4, h = bh & 15;

    const bf16_t* kvb = kv_frag + (size_t)bh * KV_BH_ELEMS + (size_t)lane * 8;

    auto load_k = [&](int tile, bf16x8 kf[4]) {
        const bf16_t* tp = kvb + (size_t)tile * KV_TILE_ELEMS;
        #pragma unroll
        for (int c = 0; c < 4; ++c) kf[c] = *(const bf16x8*)(tp + c * 512);
    };
    auto load_v = [&](int tile, bf16x8 vf[4]) {
        const bf16_t* tp = kvb + (size_t)tile * KV_TILE_ELEMS + 2048;
        #pragma unroll
        for (int i = 0; i < 4; ++i) vf[i] = *(const bf16x8*)(tp + i * 512);
    };

    #pragma unroll 1
    for (int pass = 0; pass < 2; ++pass) {
        const int qblock = pass ? (63 - p) : p;
        const int q0 = qblock * 32;
        const int nt  = qblock + 1;
        const int mid = nt >> 1;
        const int tstart = khalf ? mid : 0;
        const int tend   = khalf ? nt  : mid;

        bf16x8 qF[4];
        const bf16_t* qrow = q_ws + kv_base + (size_t)(q0 + ql) * HD + hb * 8;
        #pragma unroll
        for (int c = 0; c < 4; ++c) qF[c] = *(const bf16x8*)(qrow + 16 * c);

        f32x16 accT0 = {}, accT1 = {};
        float lsum = 0.f;

        auto compute_tile = [&](const bf16x8 kf[4], const bf16x8 vf[4], bool diag) {
            f32x16 s = {};
            #pragma unroll
            for (int c = 0; c < 4; ++c)
                s = __builtin_amdgcn_mfma_f32_32x32x16_bf16(kf[c], qF[c], s, 0, 0, 0);
            if (diag) {
                #pragma unroll
                for (int rr = 0; rr < 16; ++rr) {
                    const int kloc = (rr & 3) + 8 * (rr >> 2) + 4 * hb;
                    if (kloc > ql) s[rr] = -1e30f;
                }
            }
            #pragma unroll
            for (int rr = 0; rr < 16; ++rr) s[rr] = fast_exp2(s[rr]);
            f32x8 t8 = __builtin_shufflevector(s, s, 0, 1, 2, 3, 4, 5, 6, 7) +
                       __builtin_shufflevector(s, s, 8, 9, 10, 11, 12, 13, 14, 15);
            f32x4 t4 = __builtin_shufflevector(t8, t8, 0, 1, 2, 3) +
                       __builtin_shufflevector(t8, t8, 4, 5, 6, 7);
            lsum += (t4[0] + t4[1]) + (t4[2] + t4[3]);

            unsigned w[8];
            #pragma unroll
            for (int i = 0; i < 8; ++i) {
                unsigned d;
                asm("v_cvt_pk_bf16_f32 %0, %1, %2" : "=v"(d) : "v"(s[2 * i]), "v"(s[2 * i + 1]));
                w[i] = d;
            }
            union { unsigned u[4]; bf16x8 v; } pf0, pf1;
            {
                auto r0 = __builtin_amdgcn_permlane32_swap(w[0], w[2], false, false);
                auto r1 = __builtin_amdgcn_permlane32_swap(w[1], w[3], false, false);
                pf0.u[0] = r0[0]; pf0.u[1] = r1[0]; pf0.u[2] = r0[1]; pf0.u[3] = r1[1];
            }
            {
                auto r0 = __builtin_amdgcn_permlane32_swap(w[4], w[6], false, false);
                auto r1 = __builtin_amdgcn_permlane32_swap(w[5], w[7], false, false);
                pf1.u[0] = r0[0]; pf1.u[1] = r1[0]; pf1.u[2] = r0[1]; pf1.u[3] = r1[1];
            }

            accT0 = __builtin_amdgcn_mfma_f32_32x32x16_bf16(vf[0], pf0.v, accT0, 0, 0, 0);
            accT1 = __builtin_amdgcn_mfma_f32_32x32x16_bf16(vf[1], pf0.v, accT1, 0, 0, 0);
            accT0 = __builtin_amdgcn_mfma_f32_32x32x16_bf16(vf[2], pf1.v, accT0, 0, 0, 0);
            accT1 = __builtin_amdgcn_mfma_f32_32x32x16_bf16(vf[3], pf1.v, accT1, 0, 0, 0);
        };

        int t = tstart;
        for (; t + 1 < tend; t += 2) {
            bf16x8 kA[4], vA[4], kB[4], vB[4];
            load_k(t, kA);
            load_v(t, vA);
            load_k(t + 1, kB);
            load_v(t + 1, vB);
            compute_tile(kA, vA, t == qblock);
            compute_tile(kB, vB, (t + 1) == qblock);
        }
        if (t < tend) {
            bf16x8 kA[4], vA[4];
            load_k(t, kA);
            load_v(t, vA);
            compute_tile(kA, vA, t == qblock);
        }

        if (khalf) {
            *(f32x16*)&MRG[pr][0][lane][0] = accT0;
            *(f32x16*)&MRG[pr][1][lane][0] = accT1;
            LSUM[pr][lane] = lsum;
        }
        __syncthreads();
        if (!khalf) {
            accT0 += *(const f32x16*)&MRG[pr][0][lane][0];
            accT1 += *(const f32x16*)&MRG[pr][1][lane][0];
            lsum  += LSUM[pr][lane];
            const float ltot = lsum + __shfl_xor(lsum, 32, 64);
            const float inv  = 1.0f / ltot;
            #pragma unroll
            for (int rr = 0; rr < 16; ++rr) {
                const int dl = (rr & 3) + 8 * (rr >> 2) + 4 * hb;
                T[pr][ql][dl]      = (bf16_t)(accT0[rr] * inv);
                T[pr][ql][32 + dl] = (bf16_t)(accT1[rr] * inv);
            }
            asm volatile("s_waitcnt lgkmcnt(0)" ::: "memory");
            // grouped fragment output: idx = (((mt>>2)*32 + ks)*4 + (mt&3))*512 + lane*8
            const int mtb = (b * S_ + q0) >> 4;
            #pragma unroll
            for (int c = 0; c < 4; ++c) {
                const int mt_l = c >> 1, ks_l = c & 1;
                const int mt = mtb + mt_l, ks = h * 2 + ks_l;
                bf16x8 o = *(const bf16x8*)&T[pr][mt_l * 16 + (lane & 15)]
                                             [ks_l * 32 + ((lane >> 4) & 3) * 8];
                *(bf16x8*)(ofrag + ((((size_t)(mt >> 2) * 32 + ks) * 4) + (mt & 3)) * 512 + lane * 8) = o;
            }
        }
        __syncthreads();
    }
}

// ---------------- GEMM 2: out = attn @ w_out^T (fragment streaming, fp32 store) ----------------
__global__ __launch_bounds__(256) void gemm_out_kernel(const bf16_t* __restrict__ ofrag,
                                                       const bf16_t* __restrict__ wofrag,
                                                       float* __restrict__ out) {
    const int bid = blockIdx.x;                 // 0..511
    const int xcd = bid & 7, idx = bid >> 3;    // idx 0..63
    const int m_blk = xcd * 8 + (idx & 7);      // 0..63
    const int n_blk = idx >> 3;                 // 0..7
    const int lane = threadIdx.x & 63, wv = threadIdx.x >> 6;
    const int wm = wv >> 1, wn = wv & 1;

    f32x4 acc[4][4];
    #pragma unroll
    for (int m = 0; m < 4; ++m)
        #pragma unroll
        for (int n = 0; n < 4; ++n) acc[m][n] = f32x4{0.f, 0.f, 0.f, 0.f};

    frag_gemm_core(ofrag, wofrag, m_blk * 8 + wm * 4, n_blk * 8 + wn * 4, lane, acc);

    const int m0 = m_blk * 128, n0 = n_blk * 128;
    const int lo = lane & 15, hi = lane >> 4;
    #pragma unroll
    for (int m = 0; m < 4; ++m) {
        #pragma unroll
        for (int n = 0; n < 4; ++n) {
            const int gcol = n0 + wn * 64 + n * 16 + lo;
            #pragma unroll
            for (int j = 0; j < 4; ++j) {
                const int grow = m0 + wm * 64 + m * 16 + hi * 4 + j;
                out[(size_t)grow * D_ + gcol] = acc[m][n][j];
            }
        }
    }
}

extern "C" void kernel_launch(void* const* d_in, const int* in_sizes, int n_in,
                              void* d_out, int out_size, void* d_ws, size_t ws_size,
                              hipStream_t stream) {
    (void)in_sizes; (void)n_in; (void)out_size; (void)ws_size;
    const float* x     = (const float*)d_in[0];
    // d_in[1] = mask (known causal, unused)
    const float* w_qkv = (const float*)d_in[2];
    const float* w_out = (const float*)d_in[3];
    float* out = (float*)d_out;
    char* ws = (char*)d_ws;

    bf16_t* afrag   = (bf16_t*)(ws);                 // 16,777,216 B (x, grouped frag)
    bf16_t* wfrag   = (bf16_t*)(ws + 16777216);      //  6,291,456 B (w_qkv, grouped frag)
    bf16_t* wofrag  = (bf16_t*)(ws + 23068672);      //  2,097,152 B (w_out, grouped frag)
    bf16_t* q_ws    = (bf16_t*)(ws + 25165824);      // 16,777,216 B
    bf16_t* kv_frag = (bf16_t*)(ws + 41943040);      // 33,554,432 B (K+V fragment-native)
    bf16_t* ofrag   = (bf16_t*)(ws + 75497472);      // 16,777,216 B (attn out, grouped frag)

    cvt_frag_kernel<<<512, 256, 0, stream>>>(x, afrag);
    cvt_frag_kernel<<<192, 256, 0, stream>>>(w_qkv, wfrag);
    cvt_frag_kernel<<<64, 256, 0, stream>>>(w_out, wofrag);

    gemm_qkv_kernel<<<1536, 256, 0, stream>>>(afrag, wfrag, out, q_ws, kv_frag);
    build_vfrag_kernel<<<dim3(64, 32), 256, 0, stream>>>(out + 16777216, kv_frag);
    attn_kernel<<<1024, 256, 0, stream>>>(q_ws, kv_frag, ofrag);
    gemm_out_kernel<<<512, 256, 0, stream>>>(ofrag, wofrag, out);
}